// Round 1
// baseline (642.236 us; speedup 1.0000x reference)
//
#include <hip/hip_runtime.h>

#define TSTEPS 512   // LSTM sequence length (2048/4)
#define HID    64
#define B4H    256   // 4*HID

__device__ __forceinline__ float sigm(float x) {
  return 1.0f / (1.0f + __expf(-x));
}
__device__ __forceinline__ float tanhf_(float x) {
  // tanh(x) = 1 - 2/(exp(2x)+1); exact at +-inf, fine vs 5e-3 threshold
  return 1.0f - 2.0f / (1.0f + __expf(2.0f * x));
}

// ---------------------------------------------------------------------------
// Kernel 1: conv1 (3->16, k=3, same) + maxpool2.  x:[256,2048,3] -> t1:[256,1024,16]
// one thread per (b, pooled position), computes all 16 channels.
// ---------------------------------------------------------------------------
__global__ __launch_bounds__(256) void conv1_pool(
    const float* __restrict__ x, const float* __restrict__ w,
    const float* __restrict__ bias, float* __restrict__ out) {
  __shared__ float ws[144];  // [16][3][3]
  __shared__ float bs[16];
  const int tid = threadIdx.x;
  if (tid < 144) ws[tid] = w[tid];
  if (tid < 16)  bs[tid] = bias[tid];
  __syncthreads();

  const int idx = blockIdx.x * 256 + tid;   // b*1024 + t2
  const int b  = idx >> 10;
  const int t2 = idx & 1023;
  const float* xb = x + (size_t)b * 2048 * 3;
  const int p0 = 2 * t2;

  float xv[4][3];
#pragma unroll
  for (int j = 0; j < 4; ++j) {
    const int p = p0 - 1 + j;
    const bool ok = (p >= 0) && (p < 2048);
#pragma unroll
    for (int c = 0; c < 3; ++c) xv[j][c] = ok ? xb[p * 3 + c] : 0.0f;
  }

  float4 o4[4];
  float* op = (float*)o4;
#pragma unroll
  for (int o = 0; o < 16; ++o) {
    float s0 = bs[o], s1 = bs[o];
#pragma unroll
    for (int c = 0; c < 3; ++c) {
#pragma unroll
      for (int k = 0; k < 3; ++k) {
        const float wv = ws[(o * 3 + c) * 3 + k];
        s0 = fmaf(xv[k][c],     wv, s0);
        s1 = fmaf(xv[k + 1][c], wv, s1);
      }
    }
    op[o] = fmaxf(s0, s1);
  }
  float4* dst = (float4*)(out + (size_t)idx * 16);
  dst[0] = o4[0]; dst[1] = o4[1]; dst[2] = o4[2]; dst[3] = o4[3];
}

// ---------------------------------------------------------------------------
// Kernel 2: conv2 (16->32, k=3, same) + maxpool2. t1:[256,1024,16] -> feat:[256,512,32]
// one thread per (b, pooled position), all 32 channels.
// ---------------------------------------------------------------------------
__global__ __launch_bounds__(256) void conv2_pool(
    const float* __restrict__ t1, const float* __restrict__ w,
    const float* __restrict__ bias, float* __restrict__ out) {
  __shared__ float ws[1536];  // [32][16][3]
  __shared__ float bs[32];
  const int tid = threadIdx.x;
  for (int i = tid; i < 1536; i += 256) ws[i] = w[i];
  if (tid < 32) bs[tid] = bias[tid];
  __syncthreads();

  const int idx = blockIdx.x * 256 + tid;   // b*512 + t2
  const int b  = idx >> 9;
  const int t2 = idx & 511;
  const float* tb = t1 + (size_t)b * 1024 * 16;
  const int p0 = 2 * t2;

  float4 r4[4][4];
  float* r = (float*)r4;   // r[j*16 + c]
#pragma unroll
  for (int j = 0; j < 4; ++j) {
    const int p = p0 - 1 + j;
    if (p >= 0 && p < 1024) {
      const float4* s = (const float4*)(tb + p * 16);
      r4[j][0] = s[0]; r4[j][1] = s[1]; r4[j][2] = s[2]; r4[j][3] = s[3];
    } else {
      const float4 z = {0.f, 0.f, 0.f, 0.f};
      r4[j][0] = z; r4[j][1] = z; r4[j][2] = z; r4[j][3] = z;
    }
  }

  float4 o4[8];
  float* op = (float*)o4;
#pragma unroll 4
  for (int o = 0; o < 32; ++o) {
    float s0 = bs[o], s1 = bs[o];
    const float* wo = &ws[o * 48];
#pragma unroll
    for (int c = 0; c < 16; ++c) {
      const float w0 = wo[c * 3], w1 = wo[c * 3 + 1], w2 = wo[c * 3 + 2];
      s0 = fmaf(r[0 * 16 + c], w0, s0);
      s0 = fmaf(r[1 * 16 + c], w1, s0);
      s0 = fmaf(r[2 * 16 + c], w2, s0);
      s1 = fmaf(r[1 * 16 + c], w0, s1);
      s1 = fmaf(r[2 * 16 + c], w1, s1);
      s1 = fmaf(r[3 * 16 + c], w2, s1);
    }
    op[o] = fmaxf(s0, s1);
  }
  float4* dst = (float4*)(out + (size_t)idx * 32);
#pragma unroll
  for (int q = 0; q < 8; ++q) dst[q] = o4[q];
}

// ---------------------------------------------------------------------------
// Kernel 3: fused 2-layer LSTM + fc, one block per batch element (256 blocks
// x 512 threads).  Layer1 is pipelined one step behind layer0 so the
// sequential depth is 513 iters, not 1024.
//   threads   0..255: layer0 gate pre-activations (gate g = tid)
//   threads 256..511: layer1 gate pre-activations (gate g = tid-256)
//   update:  threads 0..63 finish layer0 unit u; 64..127 finish layer1 unit u.
// Gate weights live in VGPRs (~128/thread); h-state broadcast via LDS.
// ---------------------------------------------------------------------------
__global__ __launch_bounds__(512, 2) void lstm_fused(
    const float* __restrict__ feat,
    const float* __restrict__ w_ih0, const float* __restrict__ w_hh0,
    const float* __restrict__ b_ih0, const float* __restrict__ b_hh0,
    const float* __restrict__ w_ih1, const float* __restrict__ w_hh1,
    const float* __restrict__ b_ih1, const float* __restrict__ b_hh1,
    const float* __restrict__ fc_w, const float* __restrict__ fc_b,
    float* __restrict__ out) {
  __shared__ float4 featL[256 * 8];   // 32 KB: half of this batch's feat rows
  __shared__ float4 h0b[2][16];       // h0 double buffer (64 floats each)
  __shared__ float4 h1b[2][16];
  __shared__ float  pre[512];         // gate pre-activations (256 per layer)

  const int tid = threadIdx.x;
  const int b = blockIdx.x;

  // ---- load this thread's weight rows into registers ----
  float wx[64], wh[64], biasg;
  if (tid < 256) {
    const float4* sx = (const float4*)(w_ih0 + (size_t)tid * 32);
#pragma unroll
    for (int k = 0; k < 8; ++k) ((float4*)wx)[k] = sx[k];
    const float4* sh = (const float4*)(w_hh0 + (size_t)tid * 64);
#pragma unroll
    for (int k = 0; k < 16; ++k) ((float4*)wh)[k] = sh[k];
    biasg = b_ih0[tid] + b_hh0[tid];
  } else {
    const int g = tid - 256;
    const float4* sx = (const float4*)(w_ih1 + (size_t)g * 64);
#pragma unroll
    for (int k = 0; k < 16; ++k) ((float4*)wx)[k] = sx[k];
    const float4* sh = (const float4*)(w_hh1 + (size_t)g * 64);
#pragma unroll
    for (int k = 0; k < 16; ++k) ((float4*)wh)[k] = sh[k];
    biasg = b_ih1[g] + b_hh1[g];
  }

  // zero h state
  if (tid < 64) {
    ((float*)h0b)[tid] = 0.0f; ((float*)h0b)[64 + tid] = 0.0f;
    ((float*)h1b)[tid] = 0.0f; ((float*)h1b)[64 + tid] = 0.0f;
  }

  const float4* fg = (const float4*)(feat + (size_t)b * TSTEPS * 32);
  float cc = 0.0f;  // cell state for update threads (layer0: tid<64, layer1: 64..127)

  for (int t = 0; t <= TSTEPS; ++t) {
    // refill feat LDS in 256-row halves (block-uniform condition)
    if ((t & 255) == 0 && t < TSTEPS) {
      __syncthreads();
      const float4* src = fg + t * 8;
#pragma unroll
      for (int k = 0; k < 4; ++k) featL[tid + k * 512] = src[tid + k * 512];
    }
    __syncthreads();   // barrier A: h writes + refill visible

    if (tid < 256) {
      if (t < TSTEPS) {
        float a0 = biasg, a1 = 0.f, a2 = 0.f, a3 = 0.f;
        const float4* xt = &featL[(t & 255) * 8];
#pragma unroll
        for (int k = 0; k < 8; ++k) {
          const float4 v = xt[k];
          a0 = fmaf(wx[4 * k],     v.x, a0);
          a1 = fmaf(wx[4 * k + 1], v.y, a1);
          a2 = fmaf(wx[4 * k + 2], v.z, a2);
          a3 = fmaf(wx[4 * k + 3], v.w, a3);
        }
        const float4* hp = h0b[(t + 1) & 1];   // h0[t-1]
#pragma unroll
        for (int k = 0; k < 16; ++k) {
          const float4 v = hp[k];
          a0 = fmaf(wh[4 * k],     v.x, a0);
          a1 = fmaf(wh[4 * k + 1], v.y, a1);
          a2 = fmaf(wh[4 * k + 2], v.z, a2);
          a3 = fmaf(wh[4 * k + 3], v.w, a3);
        }
        pre[tid] = (a0 + a1) + (a2 + a3);
      }
    } else {
      if (t >= 1) {
        float a0 = biasg, a1 = 0.f, a2 = 0.f, a3 = 0.f;
        const float4* xp = h0b[(t + 1) & 1];   // h0[t-1] (layer1 input)
#pragma unroll
        for (int k = 0; k < 16; ++k) {
          const float4 v = xp[k];
          a0 = fmaf(wx[4 * k],     v.x, a0);
          a1 = fmaf(wx[4 * k + 1], v.y, a1);
          a2 = fmaf(wx[4 * k + 2], v.z, a2);
          a3 = fmaf(wx[4 * k + 3], v.w, a3);
        }
        const float4* hp = h1b[t & 1];         // h1[t-2]
#pragma unroll
        for (int k = 0; k < 16; ++k) {
          const float4 v = hp[k];
          a0 = fmaf(wh[4 * k],     v.x, a0);
          a1 = fmaf(wh[4 * k + 1], v.y, a1);
          a2 = fmaf(wh[4 * k + 2], v.z, a2);
          a3 = fmaf(wh[4 * k + 3], v.w, a3);
        }
        pre[tid] = (a0 + a1) + (a2 + a3);
      }
    }
    __syncthreads();   // barrier B: pre[] visible

    if (tid < 64) {
      if (t < TSTEPS) {           // layer0 update, unit u = tid, time t
        const float pi = pre[tid], pf = pre[64 + tid];
        const float pg = pre[128 + tid], po = pre[192 + tid];
        const float i = sigm(pi), f = sigm(pf);
        const float g = tanhf_(pg), o = sigm(po);
        cc = fmaf(f, cc, i * g);
        ((float*)h0b[t & 1])[tid] = o * tanhf_(cc);
      }
    } else if (tid < 128) {
      if (t >= 1) {               // layer1 update, unit u, time t-1
        const int u = tid - 64;
        const float pi = pre[256 + u], pf = pre[320 + u];
        const float pg = pre[384 + u], po = pre[448 + u];
        const float i = sigm(pi), f = sigm(pf);
        const float g = tanhf_(pg), o = sigm(po);
        cc = fmaf(f, cc, i * g);
        ((float*)h1b[(t + 1) & 1])[u] = o * tanhf_(cc);
      }
    }
  }
  __syncthreads();

  // fc epilogue: out[b, 0..4] from h1[T-1] (written at iter T into h1b[(T+1)&1])
  if (tid < 5) {
    const float* h = (const float*)h1b[(TSTEPS + 1) & 1];
    float s = fc_b[tid];
    const float* wrow = fc_w + tid * HID;
#pragma unroll
    for (int j = 0; j < HID; ++j) s = fmaf(wrow[j], h[j], s);
    out[b * 5 + tid] = s;
  }
}

// ---------------------------------------------------------------------------
extern "C" void kernel_launch(void* const* d_in, const int* in_sizes, int n_in,
                              void* d_out, int out_size, void* d_ws, size_t ws_size,
                              hipStream_t stream) {
  (void)in_sizes; (void)n_in; (void)out_size; (void)ws_size;
  const float* x    = (const float*)d_in[0];
  const float* c1w  = (const float*)d_in[1];
  const float* c1b  = (const float*)d_in[2];
  const float* c2w  = (const float*)d_in[3];
  const float* c2b  = (const float*)d_in[4];
  const float* wih0 = (const float*)d_in[5];
  const float* whh0 = (const float*)d_in[6];
  const float* bih0 = (const float*)d_in[7];
  const float* bhh0 = (const float*)d_in[8];
  const float* wih1 = (const float*)d_in[9];
  const float* whh1 = (const float*)d_in[10];
  const float* bih1 = (const float*)d_in[11];
  const float* bhh1 = (const float*)d_in[12];
  const float* fcw  = (const float*)d_in[13];
  const float* fcb  = (const float*)d_in[14];
  float* out = (float*)d_out;

  float* t1   = (float*)d_ws;                       // [256,1024,16] = 16 MB
  float* feat = t1 + (size_t)256 * 1024 * 16;       // [256,512,32]  = 16 MB

  conv1_pool<<<1024, 256, 0, stream>>>(x, c1w, c1b, t1);
  conv2_pool<<<512, 256, 0, stream>>>(t1, c2w, c2b, feat);
  lstm_fused<<<256, 512, 0, stream>>>(feat, wih0, whh0, bih0, bhh0,
                                      wih1, whh1, bih1, bhh1, fcw, fcb, out);
}